// Round 1
// baseline (3011.188 us; speedup 1.0000x reference)
//
#include <hip/hip_runtime.h>
#include <cstdint>
#include <cstddef>

typedef __attribute__((ext_vector_type(8))) short s16x8;
typedef __attribute__((ext_vector_type(4))) float f32x4;

#define HID 1024
#define BATCH 32
#define SEQ 512

__device__ __forceinline__ short f2bf(float f){
  unsigned u = __builtin_bit_cast(unsigned, f);
  u = (u + 0x7fffu + ((u >> 16) & 1u)) >> 16;
  return (short)u;
}
__device__ __forceinline__ float bf2f(short s){
  unsigned u = ((unsigned)(unsigned short)s) << 16;
  return __builtin_bit_cast(float, u);
}

// ---------------- pack x into A-fragment tiles ----------------
// xpk layout: [mb(128)][kt(16)] tiles of 1024 units; unit = (ks*8+mt)*64+lane,
// holds x[mb*128+mt*16+(lane&15)][kt*64+ks*32+(lane>>4)*8 + j], j=0..7
__global__ __launch_bounds__(256) void pack_x_kernel(const float* __restrict__ x,
                                                     s16x8* __restrict__ xpk){
  int P = blockIdx.x * 256 + threadIdx.x;      // 2,097,152 total
  int lane = P & 63;
  int w = (P >> 6) & 15; int ks = w >> 3, mt = w & 7;
  int tile = P >> 10; int kt = tile & 15; int mb = tile >> 4;
  int row = mb * 128 + mt * 16 + (lane & 15);
  int k0 = kt * 64 + ks * 32 + (lane >> 4) * 8;
  const f32x4* src = (const f32x4*)(x + (size_t)row * HID + k0);
  f32x4 v0 = src[0], v1 = src[1];
  s16x8 o;
  o[0]=f2bf(v0[0]); o[1]=f2bf(v0[1]); o[2]=f2bf(v0[2]); o[3]=f2bf(v0[3]);
  o[4]=f2bf(v1[0]); o[5]=f2bf(v1[1]); o[6]=f2bf(v1[2]); o[7]=f2bf(v1[3]);
  xpk[P] = o;
}

// ---------------- pack input weights (4 gates side by side, N=4096) ----------------
// B-fragment tiles: [nb(32)][kt(16)]; unit = (ks*8+nt)*64+lane holds
// W_gate[k][c] with n = nb*128+nt*16+(lane&15), gate=n>>10, c=n&1023,
// k = kt*64+ks*32+(lane>>4)*8 + j
__global__ __launch_bounds__(256) void pack_wx_kernel(const float* __restrict__ Wii,
    const float* __restrict__ Wif, const float* __restrict__ Wig,
    const float* __restrict__ Wio, s16x8* __restrict__ wxpk){
  int P = blockIdx.x * 256 + threadIdx.x;      // 524,288 total
  int lane = P & 63;
  int w = (P >> 6) & 15; int ks = w >> 3, nt = w & 7;
  int tile = P >> 10; int kt = tile & 15; int nb = tile >> 4;
  int n = nb * 128 + nt * 16 + (lane & 15);
  int g = n >> 10, c = n & 1023;
  int k0 = kt * 64 + ks * 32 + (lane >> 4) * 8;
  const float* W = (g == 0) ? Wii : (g == 1) ? Wif : (g == 2) ? Wig : Wio;
  s16x8 o;
  #pragma unroll
  for (int j = 0; j < 8; ++j) o[j] = f2bf(W[(size_t)(k0 + j) * HID + c]);
  wxpk[P] = o;
}

// ---------------- pack recurrent weights per step-kernel workgroup ----------------
// whpk: [wg(128)][kt(16)][ks(2)][nt(2)][lane][8]; col16=lane&15,
// gate = nt*2 + (col16>>3), c = wg*8 + (col16&7), k = kt*64+ks*32+(lane>>4)*8+j
__global__ __launch_bounds__(256) void pack_wh_kernel(const float* __restrict__ Whi,
    const float* __restrict__ Whf, const float* __restrict__ Whg,
    const float* __restrict__ Who, s16x8* __restrict__ whpk){
  int P = blockIdx.x * 256 + threadIdx.x;      // 524,288 total
  int lane = P & 63;
  int q = P >> 6;
  int nt = q & 1; int ks = (q >> 1) & 1; int kt = (q >> 2) & 15; int wg = q >> 6;
  int col16 = lane & 15;
  int g = nt * 2 + (col16 >> 3);
  int c = wg * 8 + (col16 & 7);
  int k0 = kt * 64 + ks * 32 + (lane >> 4) * 8;
  const float* W = (g == 0) ? Whi : (g == 1) ? Whf : (g == 2) ? Whg : Who;
  s16x8 o;
  #pragma unroll
  for (int j = 0; j < 8; ++j) o[j] = f2bf(W[(size_t)(k0 + j) * HID + c]);
  whpk[P] = o;
}

// ---------------- init: bias sums, h0 packed, c0 state ----------------
__global__ __launch_bounds__(256) void init_kernel(const float* __restrict__ h0,
    const float* __restrict__ c0,
    const float* bii, const float* bif, const float* big, const float* bio,
    const float* bhi, const float* bhf, const float* bhg, const float* bho,
    float* __restrict__ bias_sum, s16x8* __restrict__ hA0, float* __restrict__ c_state){
  int T = blockIdx.x * 256 + threadIdx.x;
  if (T < 4096){
    int g = T >> 10, c = T & 1023;
    const float* bi = (g == 0) ? bii : (g == 1) ? bif : (g == 2) ? big : bio;
    const float* bh = (g == 0) ? bhi : (g == 1) ? bhf : (g == 2) ? bhg : bho;
    bias_sum[T] = bi[c] + bh[c];
  } else if (T < 8192){
    int u = T - 4096;                 // 4096 units of 8 bf16
    int lane = u & 63; int q = u >> 6;
    int kstep = q & 31; int mtb = q >> 5;
    int b = mtb * 16 + (lane & 15);
    int col0 = kstep * 32 + (lane >> 4) * 8;
    const float* src = h0 + (size_t)b * HID + col0;
    s16x8 o;
    #pragma unroll
    for (int j = 0; j < 8; ++j) o[j] = f2bf(src[j]);
    hA0[u] = o;
  } else if (T < 12288){
    int u = T - 8192;                 // 4096 threads x 8 floats
    const f32x4* s = (const f32x4*)(c0 + (size_t)u * 8);
    f32x4* d = (f32x4*)(c_state + (size_t)u * 8);
    d[0] = s[0]; d[1] = s[1];
  }
}

// ---------------- phase 1: XP = x @ [Wii|Wif|Wig|Wio] + (b_i + b_h) ----------------
// 128x128 tile, BK=64, 4 waves, 4x4 frags each. Output scattered to XP[t][b][g][c] bf16.
__global__ __launch_bounds__(256) void gemm_xp_kernel(const s16x8* __restrict__ xpk,
    const s16x8* __restrict__ wxpk, const float* __restrict__ bias_sum,
    short* __restrict__ XP){
  const int mb = blockIdx.x, nb = blockIdx.y;
  const int tid = threadIdx.x, lane = tid & 63, wave = tid >> 6;
  const int wr = wave >> 1, wc = wave & 1;
  __shared__ s16x8 sA[1024];   // 16KB
  __shared__ s16x8 sB[1024];   // 16KB
  f32x4 acc[4][4] = {};
  const s16x8* gA = xpk + (size_t)(mb * 16) * 1024;
  const s16x8* gB = wxpk + (size_t)(nb * 16) * 1024;
  for (int kt = 0; kt < 16; ++kt){
    __syncthreads();
    #pragma unroll
    for (int i = 0; i < 4; ++i){
      sA[i * 256 + tid] = gA[(size_t)kt * 1024 + i * 256 + tid];
      sB[i * 256 + tid] = gB[(size_t)kt * 1024 + i * 256 + tid];
    }
    __syncthreads();
    #pragma unroll
    for (int ks = 0; ks < 2; ++ks){
      s16x8 af[4], bfr[4];
      #pragma unroll
      for (int i = 0; i < 4; ++i) af[i] = sA[(ks * 8 + wr * 4 + i) * 64 + lane];
      #pragma unroll
      for (int j = 0; j < 4; ++j) bfr[j] = sB[(ks * 8 + wc * 4 + j) * 64 + lane];
      #pragma unroll
      for (int i = 0; i < 4; ++i)
        #pragma unroll
        for (int j = 0; j < 4; ++j)
          acc[i][j] = __builtin_amdgcn_mfma_f32_16x16x32_bf16(af[i], bfr[j], acc[i][j], 0, 0, 0);
    }
  }
  #pragma unroll
  for (int i = 0; i < 4; ++i){
    const int m_base = mb * 128 + (wr * 4 + i) * 16 + ((lane >> 4) << 2);
    #pragma unroll
    for (int j = 0; j < 4; ++j){
      const int n = nb * 128 + (wc * 4 + j) * 16 + (lane & 15);
      const float bias = bias_sum[n];
      const int g = n >> 10, c = n & 1023;
      #pragma unroll
      for (int r = 0; r < 4; ++r){
        const int m = m_base + r;
        const int tt = m & 511, bb = m >> 9;
        XP[(((size_t)((tt * 32 + bb) * 4 + g)) << 10) + c] = f2bf(acc[i][j][r] + bias);
      }
    }
  }
}

// ---------------- phase 2: one timestep ----------------
// 128 WGs; WG owns h-cols [wg*8, wg*8+8) x 4 gates = 2 MFMA n-tiles.
// wave w: (mt=w>>1, nt=w&1). h passed in fragment-packed bf16 ping-pong buffers.
__global__ __launch_bounds__(256) void lstm_step_kernel(const s16x8* __restrict__ whpk,
    const s16x8* __restrict__ hprev, s16x8* __restrict__ hnext,
    const short* __restrict__ XP, float* __restrict__ c_state,
    float* __restrict__ out, float* __restrict__ htct, int t)
{
  const int wg = blockIdx.x;
  const int tid = threadIdx.x, lane = tid & 63, wave = tid >> 6;
  const int mt = wave >> 1, nt = wave & 1;
  __shared__ float pre[32][32];   // [b][gate*8 + c]
  f32x4 acc = {0.f, 0.f, 0.f, 0.f};
  const s16x8* B = whpk + (size_t)wg * 4096;
  #pragma unroll
  for (int kk = 0; kk < 32; ++kk){
    s16x8 a = hprev[(mt * 32 + kk) * 64 + lane];
    s16x8 b = B[(kk * 2 + nt) * 64 + lane];
    acc = __builtin_amdgcn_mfma_f32_16x16x32_bf16(a, b, acc, 0, 0, 0);
  }
  const int col16 = lane & 15;
  const int prow = mt * 16 + ((lane >> 4) << 2);
  const int pcol = nt * 16 + col16;     // == gate*8 + c
  pre[prow + 0][pcol] = acc[0];
  pre[prow + 1][pcol] = acc[1];
  pre[prow + 2][pcol] = acc[2];
  pre[prow + 3][pcol] = acc[3];
  __syncthreads();
  const int b = tid >> 3, cc = tid & 7;
  const int hcol = wg * 8 + cc;
  const size_t xpbase = ((size_t)t * 32 + b) * 4096;
  float p0 = pre[b][0 * 8 + cc] + bf2f(XP[xpbase + 0 * 1024 + hcol]);
  float p1 = pre[b][1 * 8 + cc] + bf2f(XP[xpbase + 1 * 1024 + hcol]);
  float p2 = pre[b][2 * 8 + cc] + bf2f(XP[xpbase + 2 * 1024 + hcol]);
  float p3 = pre[b][3 * 8 + cc] + bf2f(XP[xpbase + 3 * 1024 + hcol]);
  float ig = 1.f / (1.f + __expf(-p0));
  float fg = 1.f / (1.f + __expf(-p1));
  float gg = tanhf(p2);
  float og = 1.f / (1.f + __expf(-p3));
  float cp = c_state[b * HID + hcol];
  float cn = fg * cp + ig * gg;
  float h  = og * tanhf(cn);
  c_state[b * HID + hcol] = cn;
  out[((size_t)b * SEQ + t) * HID + hcol] = h;
  // pack h for next step's A-fragments
  int kstep = hcol >> 5, hi = (hcol >> 3) & 3, j = hcol & 7, l16 = b & 15, bmt = b >> 4;
  ((short*)hnext)[(((bmt * 32 + kstep) * 64 + hi * 16 + l16) << 3) + j] = f2bf(h);
  if (t == SEQ - 1){
    htct[b * HID + hcol] = h;
    htct[32 * HID + b * HID + hcol] = cn;
  }
}

extern "C" void kernel_launch(void* const* d_in, const int* in_sizes, int n_in,
                              void* d_out, int out_size, void* d_ws, size_t ws_size,
                              hipStream_t stream){
  const float* x   = (const float*)d_in[0];
  const float* h0  = (const float*)d_in[1];
  const float* c0  = (const float*)d_in[2];
  const float* Wii = (const float*)d_in[3];
  const float* Wif = (const float*)d_in[4];
  const float* Wig = (const float*)d_in[5];
  const float* Wio = (const float*)d_in[6];
  const float* Whi = (const float*)d_in[7];
  const float* Whf = (const float*)d_in[8];
  const float* Whg = (const float*)d_in[9];
  const float* Who = (const float*)d_in[10];
  const float* bii = (const float*)d_in[11];
  const float* bif = (const float*)d_in[12];
  const float* big = (const float*)d_in[13];
  const float* bio = (const float*)d_in[14];
  const float* bhi = (const float*)d_in[15];
  const float* bhf = (const float*)d_in[16];
  const float* bhg = (const float*)d_in[17];
  const float* bho = (const float*)d_in[18];

  char* ws = (char*)d_ws;
  s16x8* xpk      = (s16x8*)(ws);                         // 32 MB
  s16x8* wxpk     = (s16x8*)(ws + 33554432ull);           //  8 MB
  s16x8* whpk     = (s16x8*)(ws + 41943040ull);           //  8 MB
  short* XP       = (short*)(ws + 50331648ull);           // 128 MB
  s16x8* hA0      = (s16x8*)(ws + 184549376ull);          // 64 KB
  s16x8* hA1      = (s16x8*)(ws + 184614912ull);          // 64 KB
  float* c_state  = (float*)(ws + 184680448ull);          // 128 KB
  float* bias_sum = (float*)(ws + 184811520ull);          // 16 KB

  float* out  = (float*)d_out;
  float* htct = out + (size_t)BATCH * SEQ * HID;

  pack_x_kernel<<<8192, 256, 0, stream>>>(x, xpk);
  pack_wx_kernel<<<2048, 256, 0, stream>>>(Wii, Wif, Wig, Wio, wxpk);
  pack_wh_kernel<<<2048, 256, 0, stream>>>(Whi, Whf, Whg, Who, whpk);
  init_kernel<<<48, 256, 0, stream>>>(h0, c0, bii, bif, big, bio,
                                      bhi, bhf, bhg, bho, bias_sum, hA0, c_state);
  gemm_xp_kernel<<<dim3(128, 32), 256, 0, stream>>>(xpk, wxpk, bias_sum, XP);
  for (int t = 0; t < SEQ; ++t){
    const s16x8* hp = (t & 1) ? hA1 : hA0;
    s16x8*       hn = (t & 1) ? hA0 : hA1;
    lstm_step_kernel<<<128, 256, 0, stream>>>(whpk, hp, hn, XP, c_state, out, htct, t);
  }
}